// Round 16
// baseline (178.146 us; speedup 1.0000x reference)
//
#include <hip/hip_runtime.h>

#define Bn 2
#define Ln 4096
#define Hn 8
#define Dn 64
#define NMEGA 32           // 128-key mega-tiles
#define BH_STRIDE 262144   // halves per bh in kp/vp

typedef float    f32x4  __attribute__((ext_vector_type(4)));
typedef float    f32x16 __attribute__((ext_vector_type(16)));
typedef _Float16 f16x2  __attribute__((ext_vector_type(2)));
typedef _Float16 f16x8  __attribute__((ext_vector_type(8)));
typedef unsigned int u32;
typedef u32 u32x2 __attribute__((ext_vector_type(2)));
typedef u32 u32x4 __attribute__((ext_vector_type(4)));

static __device__ __forceinline__ void gld16(const void* g, void* l){
    __builtin_amdgcn_global_load_lds(
        (const __attribute__((address_space(1))) unsigned int*)g,
        (__attribute__((address_space(3))) unsigned int*)l, 16, 0, 0);
}

static __device__ __forceinline__ u32 pkf16(float a, float b){
    auto h = __builtin_amdgcn_cvt_pkrtz(a, b);   // v_cvt_pkrtz_f16_f32
    return __builtin_bit_cast(u32, h);
}

static __device__ __forceinline__ u32x2 swp(u32 a, u32 b){
    auto r = __builtin_amdgcn_permlane32_swap(a, b, false, false);
    return __builtin_bit_cast(u32x2, r);
}

// ---- fused prep, STREAMING (R11, verified): no LDS, no barrier ----
__global__ __launch_bounds__(256)
void kvprep(const float* __restrict__ Kg, const float* __restrict__ Vg,
            _Float16* __restrict__ kp, _Float16* __restrict__ vp){
    const int t2 = blockIdx.x, bh = blockIdx.y, b = bh>>3, h = bh&7;
    const int tid = threadIdx.x;
    const int w = tid >> 6, lane = tid & 63;
    const int l31 = lane & 31, hi = lane >> 5;
    const int t = t2 >> 1, g = t2 & 1;

    // ---- K unit cc=w ----
    {
        const float* ks = Kg + (((size_t)b*Ln + t2*32 + l31)*Hn + h)*Dn + w*16 + hi*8;
        float4 a  = *(const float4*)ks;
        float4 c4 = *(const float4*)(ks + 4);
        f16x8 o;
        o[0]=(_Float16)a.x;  o[1]=(_Float16)a.y;  o[2]=(_Float16)a.z;  o[3]=(_Float16)a.w;
        o[4]=(_Float16)c4.x; o[5]=(_Float16)c4.y; o[6]=(_Float16)c4.z; o[7]=(_Float16)c4.w;
        *(f16x8*)(kp + (size_t)bh*BH_STRIDE + (size_t)t*4096
                     + (size_t)(g*4 + w)*512 + (size_t)lane*8) = o;
    }

    // ---- V unit j=w (kh=w>>1, dt=w&1) ----
    {
        const int kh = w >> 1, dt = w & 1;
        const float* vs = Vg + (((size_t)b*Ln + t2*32 + kh*16 + hi*8)*Hn + h)*Dn
                        + dt*32 + l31;
        f16x8 o;
#pragma unroll
        for(int j=0;j<8;++j) o[j] = (_Float16)vs[(size_t)j*Hn*Dn];
        *(f16x8*)(vp + (size_t)bh*BH_STRIDE + (size_t)t*4096
                     + (size_t)(g*4 + w)*512 + (size_t)lane*8) = o;
    }
}

// QK: 4-deep 32x32x16 chain from zero accumulator
static __device__ __forceinline__ f32x16 qk4(const f16x8 (&kf)[4], const f16x8 (&qf)[4]){
    f32x16 s;
#pragma unroll
    for(int r=0;r<16;++r) s[r]=0.f;
    s = __builtin_amdgcn_mfma_f32_32x32x16_f16(kf[0], qf[0], s, 0,0,0);
    s = __builtin_amdgcn_mfma_f32_32x32x16_f16(kf[1], qf[1], s, 0,0,0);
    s = __builtin_amdgcn_mfma_f32_32x32x16_f16(kf[2], qf[2], s, 0,0,0);
    s = __builtin_amdgcn_mfma_f32_32x32x16_f16(kf[3], qf[3], s, 0,0,0);
    return s;
}

// finish: exp2 -> pack -> consistent-l via fdot2 -> PV. Same ops as R8/R15.
static __device__ __forceinline__ void finish_pv(const f32x16& S, float& lac,
                                                 f32x16& o0, f32x16& o1,
                                                 const f16x8 (&vf)[4]){
    f32x16 p;
#pragma unroll
    for(int r=0;r<16;++r) p[r] = __builtin_amdgcn_exp2f(S[r]);
    u32 A0 = pkf16(p[0],p[1]),   A1 = pkf16(p[2],p[3]);
    u32 B0 = pkf16(p[4],p[5]),   B1 = pkf16(p[6],p[7]);
    u32 C0 = pkf16(p[8],p[9]),   C1 = pkf16(p[10],p[11]);
    u32 D0 = pkf16(p[12],p[13]), D1 = pkf16(p[14],p[15]);
    u32x2 r0 = swp(A0,B0), r1 = swp(A1,B1);
    u32x2 r2 = swp(C0,D0), r3 = swp(C1,D1);
    u32x4 w0 = {r0.x, r1.x, r0.y, r1.y};   // keys [0,16) of this 32-key group
    u32x4 w1 = {r2.x, r3.x, r2.y, r3.y};   // keys [16,32)
    f16x8 pa0 = __builtin_bit_cast(f16x8, w0);
    f16x8 pa1 = __builtin_bit_cast(f16x8, w1);
    const f16x2 ones = {(_Float16)1.0f, (_Float16)1.0f};
#pragma unroll
    for(int j=0;j<4;++j){
        f16x2 c0 = {pa0[2*j], pa0[2*j+1]};
        f16x2 c1 = {pa1[2*j], pa1[2*j+1]};
        lac = __builtin_amdgcn_fdot2(c0, ones, lac, false);
        lac = __builtin_amdgcn_fdot2(c1, ones, lac, false);
    }
    o0 = __builtin_amdgcn_mfma_f32_32x32x16_f16(pa0, vf[0], o0, 0,0,0);
    o0 = __builtin_amdgcn_mfma_f32_32x32x16_f16(pa1, vf[2], o0, 0,0,0);
    o1 = __builtin_amdgcn_mfma_f32_32x32x16_f16(pa0, vf[1], o1, 0,0,0);
    o1 = __builtin_amdgcn_mfma_f32_32x32x16_f16(pa1, vf[3], o1, 0,0,0);
}

// ---- main kernel: DMA-staged (zero-VGPR loads) x 4 blocks/CU x 4-way keys ----
// BOTTLENECK MODEL (R5/R8/R15 synthesis): direct loads cap at ~4 in flight
// (each b128 costs 4 VGPRs; ~112-reg waves have ~16 spare) -> 16 loads/tile
// serialize into ~4 L2-latency batches = the ~3100 cyc/wave/tile wall.
// global_load_lds uses ZERO VGPRs for data -> all 8 DMAs/thread in flight;
// consumption is 8 lane-linear ds_reads (~120 cyc, lgkm-batched, 0-conflict).
// Single 32 KB buffer + register-capture: barrier -> ds_read frags -> barrier
// -> issue next tile's DMA -> compute (DMA ~600 cyc hides under ~2000 cyc
// compute, plus cross-block overlap at 4 blocks/CU).
// Geometry: block = 256 thr = 4 waves over 64 queries; wave (kh2,g) owns a
// 32-key quarter of each 128-key mega-tile (R15 mapping). Grid (16,64) =
// 1024 blocks -> 4 blocks/CU -> 4 waves/SIMD. LDS 33.8 KB caps at 4/CU.
// Compute + epilogue numerics EXACTLY R15 (passed).
__global__ __launch_bounds__(256,2)
void attn_fwd(const float* __restrict__ Qg, float* __restrict__ Og,
              const _Float16* __restrict__ kp, const _Float16* __restrict__ vp){
    // 8448 floats = 33.8 KB. Main loop: first 32 KB = K(16 KB)|V(16 KB) tile.
    // Epilogue reuses as xb0|xb1|xl0|xl1 (8320 floats).
    __shared__ __align__(16) float xo[8448];
    _Float16* sKV = (_Float16*)xo;                 // halves: K [0,8192) V [8192,16384)

    const int tid  = threadIdx.x;
    const int lane = tid & 63, wv = tid >> 6;
    const int kh2 = wv >> 1, g = wv & 1;           // wave's 32-key quarter
    const int l31 = lane & 31, hi = lane >> 5;
    const int bh = blockIdx.x, b = bh>>3, h = bh&7;
    const int q0 = blockIdx.y*64;                  // block owns 64 queries

    const float c = 0.125f * 1.4426950408889634f;  // scale * log2(e)

    // Q B-frags (all 4 waves hold the same 64 queries): lane=query l31
    f16x8 qf[2][4];
#pragma unroll
    for(int qt=0;qt<2;++qt){
        const float* qrow = Qg + (((size_t)b*Ln + q0 + qt*32 + l31)*Hn + h)*Dn;
#pragma unroll
        for(int cc=0;cc<4;++cc){
            const float* p4 = qrow + cc*16 + hi*8;
            float4 x = *(const float4*)p4;
            float4 y = *(const float4*)(p4+4);
            f16x8 f;
            f[0]=(_Float16)(x.x*c); f[1]=(_Float16)(x.y*c);
            f[2]=(_Float16)(x.z*c); f[3]=(_Float16)(x.w*c);
            f[4]=(_Float16)(y.x*c); f[5]=(_Float16)(y.y*c);
            f[6]=(_Float16)(y.z*c); f[7]=(_Float16)(y.w*c);
            qf[qt][cc]=f;
        }
    }

    f32x16 o[2][2];
    float lac[2] = {0.f, 0.f};
#pragma unroll
    for(int qt=0;qt<2;++qt)
#pragma unroll
        for(int dt=0;dt<2;++dt)
#pragma unroll
            for(int r=0;r<16;++r) o[qt][dt][r]=0.f;

    const _Float16* kg = kp + (size_t)bh*BH_STRIDE;
    const _Float16* vg = vp + (size_t)bh*BH_STRIDE;

    // wave's quarter inside the staged tile: byte = kh2*8192 + g*4096 + lane*16
    const char* sKb = (const char*)sKV + kh2*8192 + g*4096 + lane*16;
    const char* sVb = sKb + 16384;

    // prologue: DMA mega-tile 0 (16 KB K + 16 KB V over 256 thr: 4+4 gld16)
#pragma unroll
    for(int i=0;i<4;++i){
        int u = i*256 + tid;
        gld16(kg + (size_t)u*8, sKV + (size_t)u*8);
        gld16(vg + (size_t)u*8, sKV + 8192 + (size_t)u*8);
    }

    for(int T=0; T<NMEGA; ++T){
        __syncthreads();                   // DMA of tile T complete
        // register-capture this wave's quarter (8 lane-linear ds_read_b128)
        f16x8 kf[4], vf[4];
#pragma unroll
        for(int i=0;i<4;++i){
            kf[i] = *(const f16x8*)(sKb + (i<<10));
            vf[i] = *(const f16x8*)(sVb + (i<<10));
        }
        __syncthreads();                   // all waves captured -> buffer free
        if(T+1 < NMEGA){                   // DMA next tile NOW (hides under compute)
            const _Float16* kgn = kg + (size_t)(T+1)*8192;
            const _Float16* vgn = vg + (size_t)(T+1)*8192;
#pragma unroll
            for(int i=0;i<4;++i){
                int u = i*256 + tid;
                gld16(kgn + (size_t)u*8, sKV + (size_t)u*8);
                gld16(vgn + (size_t)u*8, sKV + 8192 + (size_t)u*8);
            }
        }
        // compute from registers only (exactly R15's order)
        f32x16 S0 = qk4(kf, qf[0]);
        f32x16 S1 = qk4(kf, qf[1]);
        finish_pv(S0, lac[0], o[0][0], o[0][1], vf);
        finish_pv(S1, lac[1], o[1][0], o[1][1], vf);
    }

    // lane l and l^32 hold complementary 16-key halves of the group
    float lred[2];
#pragma unroll
    for(int qt=0;qt<2;++qt)
        lred[qt] = lac[qt] + __shfl_xor(lac[qt], 32, 64);

    // ---- epilogue: pairwise tree across the 4 waves (R15, verified) ----
    __syncthreads();                       // compute done in all waves; no DMA pending
    float* xb0 = xo;            // 64x64
    float* xb1 = xo + 4096;     // 64x64
    float* xl0 = xo + 8192;     // 64
    float* xl1 = xo + 8256;     // 64

    // phase 1: g==1 waves publish
    if(g==1){
        float* xb = kh2 ? xb1 : xb0;
        float* xl = kh2 ? xl1 : xl0;
#pragma unroll
        for(int qt=0;qt<2;++qt){
#pragma unroll
            for(int dt=0;dt<2;++dt)
#pragma unroll
                for(int r=0;r<16;++r){
                    int qr = (r&3) + 8*(r>>2) + 4*hi;
                    xb[(qt*32 + qr)*64 + dt*32 + l31] = o[qt][dt][r];
                }
            if(hi==0) xl[qt*32 + l31] = lred[qt];
        }
    }
    __syncthreads();
    // phase 2: g==0 waves absorb their kh2 partner
    if(g==0){
        float* xb = kh2 ? xb1 : xb0;
        float* xl = kh2 ? xl1 : xl0;
#pragma unroll
        for(int qt=0;qt<2;++qt){
#pragma unroll
            for(int dt=0;dt<2;++dt)
#pragma unroll
                for(int r=0;r<16;++r){
                    int qr = (r&3) + 8*(r>>2) + 4*hi;
                    o[qt][dt][r] += xb[(qt*32 + qr)*64 + dt*32 + l31];
                }
            lred[qt] += xl[qt*32 + l31];
        }
    }
    __syncthreads();
    // phase 3: wave 2 (kh2=1,g=0) publishes its kh2=1 sum
    if(wv==2){
#pragma unroll
        for(int qt=0;qt<2;++qt){
#pragma unroll
            for(int dt=0;dt<2;++dt)
#pragma unroll
                for(int r=0;r<16;++r){
                    int qr = (r&3) + 8*(r>>2) + 4*hi;
                    xb0[(qt*32 + qr)*64 + dt*32 + l31] = o[qt][dt][r];
                }
            if(hi==0) xl0[qt*32 + l31] = lred[qt];
        }
    }
    __syncthreads();
    // phase 4: wave 0 finalizes and writes out
    if(wv==0){
#pragma unroll
        for(int qt=0;qt<2;++qt){
            float inv = 1.0f/(lred[qt] + xl0[qt*32 + l31]);
            float* ob = Og + (((size_t)b*Ln + q0 + qt*32)*Hn + h)*Dn;
#pragma unroll
            for(int r=0;r<16;++r){
                int qr = (r&3) + 8*(r>>2) + 4*hi;
                float invr = __shfl(inv, qr, 64);   // lane qr holds query qr's inv
                float v0 = o[qt][0][r] + xb0[(qt*32 + qr)*64 +  0 + l31];
                float v1 = o[qt][1][r] + xb0[(qt*32 + qr)*64 + 32 + l31];
                ob[(size_t)qr*Hn*Dn +  0 + l31] = v0*invr;
                ob[(size_t)qr*Hn*Dn + 32 + l31] = v1*invr;
            }
        }
    }
}

extern "C" void kernel_launch(void* const* d_in, const int* in_sizes, int n_in,
                              void* d_out, int out_size, void* d_ws, size_t ws_size,
                              hipStream_t stream) {
    const float* Q = (const float*)d_in[0];
    const float* K = (const float*)d_in[1];
    const float* V = (const float*)d_in[2];
    float* O = (float*)d_out;

    _Float16* kp = (_Float16*)d_ws;                        // 8 MB
    _Float16* vp = (_Float16*)((char*)d_ws + (8u<<20));    // 8 MB

    kvprep<<<dim3(128, 16), dim3(256), 0, stream>>>(K, V, kp, vp);
    attn_fwd<<<dim3(16, 64), dim3(256), 0, stream>>>(Q, O, kp, vp);
}

// Round 17
// 172.390 us; speedup vs baseline: 1.0334x; 1.0334x over previous
//
#include <hip/hip_runtime.h>

#define Bn 2
#define Ln 4096
#define Hn 8
#define Dn 64
#define NMEGA 32           // 128-key mega-tiles
#define BH_STRIDE 262144   // halves per bh in kp/vp

typedef float    f32x4  __attribute__((ext_vector_type(4)));
typedef float    f32x16 __attribute__((ext_vector_type(16)));
typedef _Float16 f16x2  __attribute__((ext_vector_type(2)));
typedef _Float16 f16x8  __attribute__((ext_vector_type(8)));
typedef unsigned int u32;
typedef u32 u32x2 __attribute__((ext_vector_type(2)));
typedef u32 u32x4 __attribute__((ext_vector_type(4)));

static __device__ __forceinline__ void gld16(const void* g, void* l){
    __builtin_amdgcn_global_load_lds(
        (const __attribute__((address_space(1))) unsigned int*)g,
        (__attribute__((address_space(3))) unsigned int*)l, 16, 0, 0);
}

static __device__ __forceinline__ u32 pkf16(float a, float b){
    auto h = __builtin_amdgcn_cvt_pkrtz(a, b);   // v_cvt_pkrtz_f16_f32
    return __builtin_bit_cast(u32, h);
}

static __device__ __forceinline__ u32x2 swp(u32 a, u32 b){
    auto r = __builtin_amdgcn_permlane32_swap(a, b, false, false);
    return __builtin_bit_cast(u32x2, r);
}

// ---- fused prep, STREAMING (R11, verified): no LDS, no barrier ----
__global__ __launch_bounds__(256)
void kvprep(const float* __restrict__ Kg, const float* __restrict__ Vg,
            _Float16* __restrict__ kp, _Float16* __restrict__ vp){
    const int t2 = blockIdx.x, bh = blockIdx.y, b = bh>>3, h = bh&7;
    const int tid = threadIdx.x;
    const int w = tid >> 6, lane = tid & 63;
    const int l31 = lane & 31, hi = lane >> 5;
    const int t = t2 >> 1, g = t2 & 1;

    // ---- K unit cc=w ----
    {
        const float* ks = Kg + (((size_t)b*Ln + t2*32 + l31)*Hn + h)*Dn + w*16 + hi*8;
        float4 a  = *(const float4*)ks;
        float4 c4 = *(const float4*)(ks + 4);
        f16x8 o;
        o[0]=(_Float16)a.x;  o[1]=(_Float16)a.y;  o[2]=(_Float16)a.z;  o[3]=(_Float16)a.w;
        o[4]=(_Float16)c4.x; o[5]=(_Float16)c4.y; o[6]=(_Float16)c4.z; o[7]=(_Float16)c4.w;
        *(f16x8*)(kp + (size_t)bh*BH_STRIDE + (size_t)t*4096
                     + (size_t)(g*4 + w)*512 + (size_t)lane*8) = o;
    }

    // ---- V unit j=w (kh=w>>1, dt=w&1) ----
    {
        const int kh = w >> 1, dt = w & 1;
        const float* vs = Vg + (((size_t)b*Ln + t2*32 + kh*16 + hi*8)*Hn + h)*Dn
                        + dt*32 + l31;
        f16x8 o;
#pragma unroll
        for(int j=0;j<8;++j) o[j] = (_Float16)vs[(size_t)j*Hn*Dn];
        *(f16x8*)(vp + (size_t)bh*BH_STRIDE + (size_t)t*4096
                     + (size_t)(g*4 + w)*512 + (size_t)lane*8) = o;
    }
}

// QK: 4-deep 32x32x16 chain from zero accumulator
static __device__ __forceinline__ f32x16 qk4(const f16x8 (&kf)[4], const f16x8 (&qf)[4]){
    f32x16 s;
#pragma unroll
    for(int r=0;r<16;++r) s[r]=0.f;
    s = __builtin_amdgcn_mfma_f32_32x32x16_f16(kf[0], qf[0], s, 0,0,0);
    s = __builtin_amdgcn_mfma_f32_32x32x16_f16(kf[1], qf[1], s, 0,0,0);
    s = __builtin_amdgcn_mfma_f32_32x32x16_f16(kf[2], qf[2], s, 0,0,0);
    s = __builtin_amdgcn_mfma_f32_32x32x16_f16(kf[3], qf[3], s, 0,0,0);
    return s;
}

// finish: exp2 -> pack -> consistent-l via fdot2 -> PV. Same ops as R15/R16.
static __device__ __forceinline__ void finish_pv(const f32x16& S, float& lac,
                                                 f32x16& o0, f32x16& o1,
                                                 const f16x8 (&vf)[4]){
    f32x16 p;
#pragma unroll
    for(int r=0;r<16;++r) p[r] = __builtin_amdgcn_exp2f(S[r]);
    u32 A0 = pkf16(p[0],p[1]),   A1 = pkf16(p[2],p[3]);
    u32 B0 = pkf16(p[4],p[5]),   B1 = pkf16(p[6],p[7]);
    u32 C0 = pkf16(p[8],p[9]),   C1 = pkf16(p[10],p[11]);
    u32 D0 = pkf16(p[12],p[13]), D1 = pkf16(p[14],p[15]);
    u32x2 r0 = swp(A0,B0), r1 = swp(A1,B1);
    u32x2 r2 = swp(C0,D0), r3 = swp(C1,D1);
    u32x4 w0 = {r0.x, r1.x, r0.y, r1.y};   // keys [0,16) of this 32-key group
    u32x4 w1 = {r2.x, r3.x, r2.y, r3.y};   // keys [16,32)
    f16x8 pa0 = __builtin_bit_cast(f16x8, w0);
    f16x8 pa1 = __builtin_bit_cast(f16x8, w1);
    const f16x2 ones = {(_Float16)1.0f, (_Float16)1.0f};
#pragma unroll
    for(int j=0;j<4;++j){
        f16x2 c0 = {pa0[2*j], pa0[2*j+1]};
        f16x2 c1 = {pa1[2*j], pa1[2*j+1]};
        lac = __builtin_amdgcn_fdot2(c0, ones, lac, false);
        lac = __builtin_amdgcn_fdot2(c1, ones, lac, false);
    }
    o0 = __builtin_amdgcn_mfma_f32_32x32x16_f16(pa0, vf[0], o0, 0,0,0);
    o0 = __builtin_amdgcn_mfma_f32_32x32x16_f16(pa1, vf[2], o0, 0,0,0);
    o1 = __builtin_amdgcn_mfma_f32_32x32x16_f16(pa0, vf[1], o1, 0,0,0);
    o1 = __builtin_amdgcn_mfma_f32_32x32x16_f16(pa1, vf[3], o1, 0,0,0);
}

// ---- main kernel: WAVE-PRIVATE DMA double-use buffer, NO loop barriers ----
// Combines the session's two proven-good ingredients, never before paired:
//   (a) free-running waves (R8/R11: no barrier convoy), and
//   (b) zero-VGPR global_load_lds staging (loads never occupy registers,
//       so the allocator cannot serialize them — R13/R15's failure mode).
// Each wave owns a PRIVATE 8 KB LDS buffer (its 32-key quarter: 4 KB K +
// 4 KB V). No sharing -> no __syncthreads in the loop. Ordering is per-wave:
//   s_waitcnt vmcnt(0)   (own DMAs for tile T landed; issued a full tile
//                         ago -> ~0 cyc actual wait)
//   8x lane-linear ds_read_b128 (capture quarter to regs; conflict-free)
//   s_waitcnt lgkmcnt(0) (capture complete -> buffer reusable)
//   issue 8 DMA for tile T+1 (lands under ~2000 cyc of compute)
//   compute (register-only; exactly R15/R16's op order)
// Geometry: block = 4 waves over 64 queries, wave (kh2,g) = 32-key quarter;
// grid (16,64) = 1024 blocks -> 4 blocks/CU -> 4 waves/SIMD, all decoupled.
// LDS 33.8 KB (4x8 KB private + epilogue tail) caps residency at 4/CU.
__global__ __launch_bounds__(256,2)
void attn_fwd(const float* __restrict__ Qg, float* __restrict__ Og,
              const _Float16* __restrict__ kp, const _Float16* __restrict__ vp){
    __shared__ __align__(16) float xo[8448];       // 33.8 KB
    const int tid  = threadIdx.x;
    const int lane = tid & 63, wv = tid >> 6;
    const int kh2 = wv >> 1, g = wv & 1;           // wave's 32-key quarter
    const int l31 = lane & 31, hi = lane >> 5;
    const int bh = blockIdx.x, b = bh>>3, h = bh&7;
    const int q0 = blockIdx.y*64;                  // block owns 64 queries

    _Float16* sW = (_Float16*)xo + (size_t)wv*4096;    // private 8 KB
    _Float16* sK = sW + (size_t)lane*8;                // K half [0,2048)
    _Float16* sV = sW + 2048 + (size_t)lane*8;         // V half [2048,4096)

    const float c = 0.125f * 1.4426950408889634f;  // scale * log2(e)

    // Q B-frags (all 4 waves hold the same 64 queries): lane=query l31
    f16x8 qf[2][4];
#pragma unroll
    for(int qt=0;qt<2;++qt){
        const float* qrow = Qg + (((size_t)b*Ln + q0 + qt*32 + l31)*Hn + h)*Dn;
#pragma unroll
        for(int cc=0;cc<4;++cc){
            const float* p4 = qrow + cc*16 + hi*8;
            float4 x = *(const float4*)p4;
            float4 y = *(const float4*)(p4+4);
            f16x8 f;
            f[0]=(_Float16)(x.x*c); f[1]=(_Float16)(x.y*c);
            f[2]=(_Float16)(x.z*c); f[3]=(_Float16)(x.w*c);
            f[4]=(_Float16)(y.x*c); f[5]=(_Float16)(y.y*c);
            f[6]=(_Float16)(y.z*c); f[7]=(_Float16)(y.w*c);
            qf[qt][cc]=f;
        }
    }

    f32x16 o[2][2];
    float lac[2] = {0.f, 0.f};
#pragma unroll
    for(int qt=0;qt<2;++qt)
#pragma unroll
        for(int dt=0;dt<2;++dt)
#pragma unroll
            for(int r=0;r<16;++r) o[qt][dt][r]=0.f;

    // wave's quarter source (halves): tile T at +T*8192
    const _Float16* kq = kp + (size_t)bh*BH_STRIDE + kh2*4096 + g*2048 + (size_t)lane*8;
    const _Float16* vq = vp + (size_t)bh*BH_STRIDE + kh2*4096 + g*2048 + (size_t)lane*8;

    // prologue: DMA tile 0 into private buffer (4 K-units + 4 V-units)
#pragma unroll
    for(int i=0;i<4;++i){
        gld16(kq + i*512, sK + i*512);
        gld16(vq + i*512, sV + i*512);
    }

    for(int T=0; T<NMEGA; ++T){
        asm volatile("s_waitcnt vmcnt(0)" ::: "memory");   // own DMAs landed
        f16x8 kf[4], vf[4];
#pragma unroll
        for(int i=0;i<4;++i){
            kf[i] = *(const f16x8*)(sK + i*512);
            vf[i] = *(const f16x8*)(sV + i*512);
        }
        asm volatile("s_waitcnt lgkmcnt(0)" ::: "memory"); // capture done
        if(T+1 < NMEGA){
            const _Float16* kn = kq + (size_t)(T+1)*8192;
            const _Float16* vn = vq + (size_t)(T+1)*8192;
#pragma unroll
            for(int i=0;i<4;++i){
                gld16(kn + i*512, sK + i*512);
                gld16(vn + i*512, sV + i*512);
            }
        }
        // compute from registers only (exactly R15/R16's order)
        f32x16 S0 = qk4(kf, qf[0]);
        f32x16 S1 = qk4(kf, qf[1]);
        finish_pv(S0, lac[0], o[0][0], o[0][1], vf);
        finish_pv(S1, lac[1], o[1][0], o[1][1], vf);
    }

    // lane l and l^32 hold complementary 16-key halves of the group
    float lred[2];
#pragma unroll
    for(int qt=0;qt<2;++qt)
        lred[qt] = lac[qt] + __shfl_xor(lac[qt], 32, 64);

    // ---- epilogue: pairwise tree across the 4 waves (R15, verified) ----
    __syncthreads();                       // all captures done; no DMA pending
    float* xb0 = xo;            // 64x64
    float* xb1 = xo + 4096;     // 64x64
    float* xl0 = xo + 8192;     // 64
    float* xl1 = xo + 8256;     // 64

    // phase 1: g==1 waves publish
    if(g==1){
        float* xb = kh2 ? xb1 : xb0;
        float* xl = kh2 ? xl1 : xl0;
#pragma unroll
        for(int qt=0;qt<2;++qt){
#pragma unroll
            for(int dt=0;dt<2;++dt)
#pragma unroll
                for(int r=0;r<16;++r){
                    int qr = (r&3) + 8*(r>>2) + 4*hi;
                    xb[(qt*32 + qr)*64 + dt*32 + l31] = o[qt][dt][r];
                }
            if(hi==0) xl[qt*32 + l31] = lred[qt];
        }
    }
    __syncthreads();
    // phase 2: g==0 waves absorb their kh2 partner
    if(g==0){
        float* xb = kh2 ? xb1 : xb0;
        float* xl = kh2 ? xl1 : xl0;
#pragma unroll
        for(int qt=0;qt<2;++qt){
#pragma unroll
            for(int dt=0;dt<2;++dt)
#pragma unroll
                for(int r=0;r<16;++r){
                    int qr = (r&3) + 8*(r>>2) + 4*hi;
                    o[qt][dt][r] += xb[(qt*32 + qr)*64 + dt*32 + l31];
                }
            lred[qt] += xl[qt*32 + l31];
        }
    }
    __syncthreads();
    // phase 3: wave 2 (kh2=1,g=0) publishes its kh2=1 sum
    if(wv==2){
#pragma unroll
        for(int qt=0;qt<2;++qt){
#pragma unroll
            for(int dt=0;dt<2;++dt)
#pragma unroll
                for(int r=0;r<16;++r){
                    int qr = (r&3) + 8*(r>>2) + 4*hi;
                    xb0[(qt*32 + qr)*64 + dt*32 + l31] = o[qt][dt][r];
                }
            if(hi==0) xl0[qt*32 + l31] = lred[qt];
        }
    }
    __syncthreads();
    // phase 4: wave 0 finalizes and writes out
    if(wv==0){
#pragma unroll
        for(int qt=0;qt<2;++qt){
            float inv = 1.0f/(lred[qt] + xl0[qt*32 + l31]);
            float* ob = Og + (((size_t)b*Ln + q0 + qt*32)*Hn + h)*Dn;
#pragma unroll
            for(int r=0;r<16;++r){
                int qr = (r&3) + 8*(r>>2) + 4*hi;
                float invr = __shfl(inv, qr, 64);   // lane qr holds query qr's inv
                float v0 = o[qt][0][r] + xb0[(qt*32 + qr)*64 +  0 + l31];
                float v1 = o[qt][1][r] + xb0[(qt*32 + qr)*64 + 32 + l31];
                ob[(size_t)qr*Hn*Dn +  0 + l31] = v0*invr;
                ob[(size_t)qr*Hn*Dn + 32 + l31] = v1*invr;
            }
        }
    }
}

extern "C" void kernel_launch(void* const* d_in, const int* in_sizes, int n_in,
                              void* d_out, int out_size, void* d_ws, size_t ws_size,
                              hipStream_t stream) {
    const float* Q = (const float*)d_in[0];
    const float* K = (const float*)d_in[1];
    const float* V = (const float*)d_in[2];
    float* O = (float*)d_out;

    _Float16* kp = (_Float16*)d_ws;                        // 8 MB
    _Float16* vp = (_Float16*)((char*)d_ws + (8u<<20));    // 8 MB

    kvprep<<<dim3(128, 16), dim3(256), 0, stream>>>(K, V, kp, vp);
    attn_fwd<<<dim3(16, 64), dim3(256), 0, stream>>>(Q, O, kp, vp);
}